// Round 7
// baseline (401.717 us; speedup 1.0000x reference)
//
#include <hip/hip_runtime.h>
#include <cstddef>
#include <cstdint>

#define NHEADS 4
#define DHEAD 64
#define CIN 256
#define HID 256
#define MQKV 768
#define NPIX 4096
#define NBATCH 16
#define ATT_SCALE 0.125f
#define LN_EPS 1e-5f

typedef float f32x4 __attribute__((ext_vector_type(4)));
typedef short s16x8 __attribute__((ext_vector_type(8)));
typedef unsigned short ushort;

// workspace layout (in floats)
static constexpr size_t OFF_QKV  = 0;                                // 16*768*4096 u32
static constexpr size_t OFF_KSUM = (size_t)NBATCH * MQKV * NPIX;     // 4096 f
static constexpr size_t OFF_CTX  = OFF_KSUM + 4096;                  // 262144 f
static constexpr size_t OFF_QSUM = OFF_CTX + 262144;                 // 262144 f
static constexpr size_t OFF_WA   = OFF_QSUM + 262144;                // 1 M u32
static constexpr size_t OFF_WH   = OFF_WA + 1048576;                 // 98304 f
static constexpr size_t OFF_WL   = OFF_WH + 98304;                   // 98304 f

__device__ __forceinline__ unsigned pack_bf(float v) {
  // (bf16_hi << 16) | bf16_lo with RNE; v == hi + lo to ~2^-17 rel
  unsigned u = __float_as_uint(v);
  unsigned hi = (u + 0x7fffu + ((u >> 16) & 1u)) >> 16;
  float fh = __uint_as_float(hi << 16);
  float rr = v - fh;
  unsigned u2 = __float_as_uint(rr);
  unsigned lo = (u2 + 0x7fffu + ((u2 >> 16) & 1u)) >> 16;
  return (hi << 16) | (lo & 0xffffu);
}

__device__ __forceinline__ void gload_lds16(const void* gsrc, void* ldst) {
  __builtin_amdgcn_global_load_lds(
      (const __attribute__((address_space(1))) unsigned int*)gsrc,
      (__attribute__((address_space(3))) unsigned int*)ldst, 16, 0, 0);
}

// B-tile LDS slot swizzle (validated R6: conflicts 1.26e7 -> 3.1e6)
#define BSWZ(nl) ((((nl) & 7) ^ (((nl) >> 2) & 7)) & 7)

// ---------------------------------------------------------------------------
// P0: split W_qkv into bf16 hi/lo with 16B-piece XOR pre-swizzle. (validated)
// ---------------------------------------------------------------------------
__global__ __launch_bounds__(256) void k_wsplit(const float* __restrict__ W,
                                                ushort* __restrict__ WH,
                                                ushort* __restrict__ WL) {
  const int pid = blockIdx.x * 256 + threadIdx.x;
  const int m = pid >> 5, pp = pid & 31;
  const int wdw = pp >> 2, p = pp & 3;
  const int sp = p ^ ((m >> 1) & 3);
  const float* src = W + (size_t)m * 256 + wdw * 32 + sp * 8;
  s16x8 hv, lv;
#pragma unroll
  for (int e = 0; e < 8; ++e) {
    unsigned pk = pack_bf(src[e]);
    hv[e] = (short)(pk >> 16);
    lv[e] = (short)(pk & 0xffffu);
  }
  *(s16x8*)&WH[(size_t)m * 256 + pp * 8] = hv;
  *(s16x8*)&WL[(size_t)m * 256 + pp * 8] = lv;
}

// ---------------------------------------------------------------------------
// K1: qkv[b] = W @ X[b] via split-bf16 MFMA (structure validated R6).
// v3 epilogue fusion: q rows -> pack(exp(q)) + QSUM column-sum atomics;
// k rows -> pack(exp(k)) + KSUM row-sum atomics; v rows -> pack(v).
// Output QKVP is packed u32 (hi|lo bf16), same 4 B/elem as fp32.
// ---------------------------------------------------------------------------
__global__ __launch_bounds__(256, 2) void k_qkv_mfma(const ushort* __restrict__ WH,
                                                     const ushort* __restrict__ WL,
                                                     const float* __restrict__ X,
                                                     unsigned* __restrict__ Y,
                                                     float* __restrict__ KSUM,
                                                     float* __restrict__ QSUM) {
  __shared__ ushort AHs[2][4096];
  __shared__ ushort ALs[2][4096];
  __shared__ unsigned int BTs[2][4096];

  const int t = threadIdx.x;
  const int lane = t & 63;
  const int w = t >> 6;
  const int wy = w >> 1, wx = w & 1;

  // XCD-aware decode (validated R6)
  const int D = blockIdx.x;
  const int xcd = D & 7;
  const int jj = D >> 3;
  const int mtile = jj % 6;
  const int gi = jj / 6;
  const int grp = xcd + (gi << 3);       // 0..511 = b*32 + ntile
  const int m0 = mtile * 128;
  const int n0 = (grp & 31) * 128;
  const int b  = grp >> 5;

  const float* Xb = X + (size_t)b * CIN * NPIX;
  unsigned* Yu = Y + (size_t)b * MQKV * NPIX;

  const int r = lane & 15, g = lane >> 4;
  const int bn0 = (t & 31) * 4;
  const int bcq = t >> 5;
  const int bc0 = bcq * 4;

  f32x4 acc[4][4];
#pragma unroll
  for (int i = 0; i < 4; ++i)
#pragma unroll
    for (int j = 0; j < 4; ++j) acc[i][j] = (f32x4){0.f, 0.f, 0.f, 0.f};

  float4 bx[4];

  {
#pragma unroll
    for (int ch = 0; ch < 2; ++ch) {
      const int slot = ch * 256 + t;
      const int row = slot >> 2, pc = slot & 3;
      gload_lds16(WH + (size_t)(m0 + row) * 256 + pc * 8, &AHs[0][slot * 8]);
      gload_lds16(WL + (size_t)(m0 + row) * 256 + pc * 8, &ALs[0][slot * 8]);
    }
#pragma unroll
    for (int i = 0; i < 4; ++i)
      bx[i] = *(const float4*)&Xb[(size_t)(bc0 + i) * NPIX + n0 + bn0];
    unsigned pk[4][4];
#pragma unroll
    for (int i = 0; i < 4; ++i) {
      pk[0][i] = pack_bf(bx[i].x); pk[1][i] = pack_bf(bx[i].y);
      pk[2][i] = pack_bf(bx[i].z); pk[3][i] = pack_bf(bx[i].w);
    }
#pragma unroll
    for (int j = 0; j < 4; ++j) {
      const int nl = bn0 + j;
      const int s = bcq ^ BSWZ(nl);
      uint4 q4; q4.x = pk[j][0]; q4.y = pk[j][1]; q4.z = pk[j][2]; q4.w = pk[j][3];
      *(uint4*)&BTs[0][nl * 32 + s * 4] = q4;
    }
  }
  __syncthreads();

  for (int kc = 0; kc < 8; ++kc) {
    const int cur = kc & 1;
    const int nxt = cur ^ 1;
    if (kc < 7) {
#pragma unroll
      for (int ch = 0; ch < 2; ++ch) {
        const int slot = ch * 256 + t;
        const int row = slot >> 2, pc = slot & 3;
        gload_lds16(WH + (size_t)(m0 + row) * 256 + (kc + 1) * 32 + pc * 8, &AHs[nxt][slot * 8]);
        gload_lds16(WL + (size_t)(m0 + row) * 256 + (kc + 1) * 32 + pc * 8, &ALs[nxt][slot * 8]);
      }
#pragma unroll
      for (int i = 0; i < 4; ++i)
        bx[i] = *(const float4*)&Xb[(size_t)((kc + 1) * 32 + bc0 + i) * NPIX + n0 + bn0];
    }

    s16x8 ah[4], al[4], bh[4], bl[4];
#pragma unroll
    for (int mt = 0; mt < 4; ++mt) {
      const int mr = wy * 64 + mt * 16 + r;
      const int p = g ^ ((mr >> 1) & 3);
      ah[mt] = *(const s16x8*)&AHs[cur][mr * 32 + p * 8];
      al[mt] = *(const s16x8*)&ALs[cur][mr * 32 + p * 8];
    }
#pragma unroll
    for (int nt = 0; nt < 4; ++nt) {
      const int nl = wx * 64 + nt * 16 + r;
      const int s0 = (2 * g) ^ BSWZ(nl);
      const int s1 = (2 * g + 1) ^ BSWZ(nl);
      const uint4 u0 = *(const uint4*)&BTs[cur][nl * 32 + s0 * 4];
      const uint4 u1 = *(const uint4*)&BTs[cur][nl * 32 + s1 * 4];
      s16x8 hv, lv;
      hv[0] = (short)(u0.x >> 16); lv[0] = (short)u0.x;
      hv[1] = (short)(u0.y >> 16); lv[1] = (short)u0.y;
      hv[2] = (short)(u0.z >> 16); lv[2] = (short)u0.z;
      hv[3] = (short)(u0.w >> 16); lv[3] = (short)u0.w;
      hv[4] = (short)(u1.x >> 16); lv[4] = (short)u1.x;
      hv[5] = (short)(u1.y >> 16); lv[5] = (short)u1.y;
      hv[6] = (short)(u1.z >> 16); lv[6] = (short)u1.z;
      hv[7] = (short)(u1.w >> 16); lv[7] = (short)u1.w;
      bh[nt] = hv; bl[nt] = lv;
    }

#pragma unroll
    for (int mt = 0; mt < 4; ++mt)
#pragma unroll
      for (int nt = 0; nt < 4; ++nt) {
        acc[mt][nt] = __builtin_amdgcn_mfma_f32_16x16x32_bf16(ah[mt], bh[nt], acc[mt][nt], 0, 0, 0);
        acc[mt][nt] = __builtin_amdgcn_mfma_f32_16x16x32_bf16(ah[mt], bl[nt], acc[mt][nt], 0, 0, 0);
        acc[mt][nt] = __builtin_amdgcn_mfma_f32_16x16x32_bf16(al[mt], bh[nt], acc[mt][nt], 0, 0, 0);
      }

    if (kc < 7) {
      unsigned pk[4][4];
#pragma unroll
      for (int i = 0; i < 4; ++i) {
        pk[0][i] = pack_bf(bx[i].x); pk[1][i] = pack_bf(bx[i].y);
        pk[2][i] = pack_bf(bx[i].z); pk[3][i] = pack_bf(bx[i].w);
      }
#pragma unroll
      for (int j = 0; j < 4; ++j) {
        const int nl = bn0 + j;
        const int s = bcq ^ BSWZ(nl);
        uint4 q4; q4.x = pk[j][0]; q4.y = pk[j][1]; q4.z = pk[j][2]; q4.w = pk[j][3];
        *(uint4*)&BTs[nxt][nl * 32 + s * 4] = q4;
      }
    }
    __syncthreads();
  }

  // ---------------- fused epilogue (branch uniform per m-tile) ----------------
  if (mtile < 2) {
    // q rows: write pack(exp(q)); QSUM[b][h][n] += column sums (f32)
    float cs[4] = {0.f, 0.f, 0.f, 0.f};
#pragma unroll
    for (int mt = 0; mt < 4; ++mt) {
      const int mrow = m0 + wy * 64 + mt * 16 + g * 4;
#pragma unroll
      for (int nt = 0; nt < 4; ++nt) {
        const int ncol = n0 + wx * 64 + nt * 16 + r;
#pragma unroll
        for (int j = 0; j < 4; ++j) {
          const float e = __expf(acc[mt][nt][j]);
          cs[nt] += e;
          Yu[(size_t)(mrow + j) * NPIX + ncol] = pack_bf(e);
        }
      }
    }
    const int h = (m0 >> 6) + wy;   // head covered entirely by this wave-row
#pragma unroll
    for (int nt = 0; nt < 4; ++nt) {
      float s = cs[nt];
      s += __shfl_xor(s, 16);
      s += __shfl_xor(s, 32);
      if (g == 0)
        atomicAdd(&QSUM[((size_t)b * 4 + h) * NPIX + n0 + wx * 64 + nt * 16 + r], s);
    }
  } else if (mtile < 4) {
    // k rows: write pack(exp(k)); KSUM[b*256 + d] += row partial sums
#pragma unroll
    for (int mt = 0; mt < 4; ++mt) {
      const int mrow = m0 + wy * 64 + mt * 16 + g * 4;
#pragma unroll
      for (int j = 0; j < 4; ++j) {
        float rsum = 0.f;
#pragma unroll
        for (int nt = 0; nt < 4; ++nt) {
          const int ncol = n0 + wx * 64 + nt * 16 + r;
          const float e = __expf(acc[mt][nt][j]);
          rsum += e;
          Yu[(size_t)(mrow + j) * NPIX + ncol] = pack_bf(e);
        }
        rsum += __shfl_xor(rsum, 1);
        rsum += __shfl_xor(rsum, 2);
        rsum += __shfl_xor(rsum, 4);
        rsum += __shfl_xor(rsum, 8);
        if (r == 0)
          atomicAdd(&KSUM[b * 256 + (mrow + j - 256)], rsum);
      }
    }
  } else {
    // v rows: write pack(v)
#pragma unroll
    for (int mt = 0; mt < 4; ++mt) {
      const int mrow = m0 + wy * 64 + mt * 16 + g * 4;
#pragma unroll
      for (int nt = 0; nt < 4; ++nt) {
        const int ncol = n0 + wx * 64 + nt * 16 + r;
#pragma unroll
        for (int j = 0; j < 4; ++j)
          Yu[(size_t)(mrow + j) * NPIX + ncol] = pack_bf(acc[mt][nt][j]);
      }
    }
  }
}

// ---------------------------------------------------------------------------
// K3 v4: CTX[b,h][d][e] += sum_n exp(k)*v — operands arrive PRE-PACKED
// (exp(k) and v as u32 hi|lo) -> pure unpack + MFMA, no exp/pack VALU.
// No LDS, no barriers. Grid (64 bh, 8 chunks of 512 n).
// ---------------------------------------------------------------------------
__global__ __launch_bounds__(256) void k_context3(const unsigned* __restrict__ QKVP,
                                                  float* __restrict__ CTX) {
  const int bh = blockIdx.x;       // 64
  const int chunk = blockIdx.y;    // 8
  const int b = bh >> 2, h = bh & 3;
  const unsigned* Kb = QKVP + ((size_t)b * MQKV + HID + h * DHEAD) * NPIX;
  const unsigned* Vb = QKVP + ((size_t)b * MQKV + 2 * HID + h * DHEAD) * NPIX;
  const int t = threadIdx.x;
  const int lane = t & 63, w = t >> 6;
  const int wy = w >> 1, wx = w & 1;
  const int r = lane & 15, gq = lane >> 4;

  f32x4 acc[2][2];
#pragma unroll
  for (int i = 0; i < 2; ++i)
#pragma unroll
    for (int j = 0; j < 2; ++j) acc[i][j] = (f32x4){0.f, 0.f, 0.f, 0.f};

  const int nb = chunk * 512 + gq * 8;

  for (int step = 0; step < 16; ++step) {
    const int n0 = nb + step * 32;
    s16x8 ah2[2], al2[2], bh2[2], bl2[2];
#pragma unroll
    for (int mt = 0; mt < 2; ++mt) {
      const int d = wy * 32 + mt * 16 + r;
      const uint4 u0 = *(const uint4*)&Kb[(size_t)d * NPIX + n0];
      const uint4 u1 = *(const uint4*)&Kb[(size_t)d * NPIX + n0 + 4];
      s16x8 hv, lv;
      hv[0] = (short)(u0.x >> 16); lv[0] = (short)u0.x;
      hv[1] = (short)(u0.y >> 16); lv[1] = (short)u0.y;
      hv[2] = (short)(u0.z >> 16); lv[2] = (short)u0.z;
      hv[3] = (short)(u0.w >> 16); lv[3] = (short)u0.w;
      hv[4] = (short)(u1.x >> 16); lv[4] = (short)u1.x;
      hv[5] = (short)(u1.y >> 16); lv[5] = (short)u1.y;
      hv[6] = (short)(u1.z >> 16); lv[6] = (short)u1.z;
      hv[7] = (short)(u1.w >> 16); lv[7] = (short)u1.w;
      ah2[mt] = hv; al2[mt] = lv;
    }
#pragma unroll
    for (int nt = 0; nt < 2; ++nt) {
      const int e = wx * 32 + nt * 16 + r;
      const uint4 u0 = *(const uint4*)&Vb[(size_t)e * NPIX + n0];
      const uint4 u1 = *(const uint4*)&Vb[(size_t)e * NPIX + n0 + 4];
      s16x8 hv, lv;
      hv[0] = (short)(u0.x >> 16); lv[0] = (short)u0.x;
      hv[1] = (short)(u0.y >> 16); lv[1] = (short)u0.y;
      hv[2] = (short)(u0.z >> 16); lv[2] = (short)u0.z;
      hv[3] = (short)(u0.w >> 16); lv[3] = (short)u0.w;
      hv[4] = (short)(u1.x >> 16); lv[4] = (short)u1.x;
      hv[5] = (short)(u1.y >> 16); lv[5] = (short)u1.y;
      hv[6] = (short)(u1.z >> 16); lv[6] = (short)u1.z;
      hv[7] = (short)(u1.w >> 16); lv[7] = (short)u1.w;
      bh2[nt] = hv; bl2[nt] = lv;
    }
#pragma unroll
    for (int mt = 0; mt < 2; ++mt)
#pragma unroll
      for (int nt = 0; nt < 2; ++nt) {
        acc[mt][nt] = __builtin_amdgcn_mfma_f32_16x16x32_bf16(ah2[mt], bh2[nt], acc[mt][nt], 0, 0, 0);
        acc[mt][nt] = __builtin_amdgcn_mfma_f32_16x16x32_bf16(ah2[mt], bl2[nt], acc[mt][nt], 0, 0, 0);
        acc[mt][nt] = __builtin_amdgcn_mfma_f32_16x16x32_bf16(al2[mt], bh2[nt], acc[mt][nt], 0, 0, 0);
      }
  }

#pragma unroll
  for (int mt = 0; mt < 2; ++mt)
#pragma unroll
    for (int nt = 0; nt < 2; ++nt)
#pragma unroll
      for (int j = 0; j < 4; ++j) {
        const int d = wy * 32 + mt * 16 + gq * 4 + j;
        const int e = wx * 32 + nt * 16 + r;
        atomicAdd(&CTX[((size_t)bh * 64 + d) * 64 + e], acc[mt][nt][j]);
      }
}

// ---------------------------------------------------------------------------
// K4: WA[b][wnd][o][32] (u32 packed hi|lo, 16B-piece XOR-swizzled) =
//     transposed, scaled, folded W_out·context. (validated)
// ---------------------------------------------------------------------------
__global__ __launch_bounds__(256) void k_wct2(const float* __restrict__ Wout,
                                              const float* __restrict__ CTX,
                                              const float* __restrict__ KSUMp,
                                              unsigned* __restrict__ WA) {
  const int h = blockIdx.x, b = blockIdx.y;
  const int bh = b * 4 + h;
  const int o = threadIdx.x;
  const float* Cb = CTX + (size_t)bh * 4096;
  const float* Kb = KSUMp + bh * 64;

  float wv[64];
#pragma unroll
  for (int i = 0; i < 16; ++i) {
    float4 w4 = *(const float4*)&Wout[(size_t)o * HID + h * DHEAD + i * 4];
    wv[i * 4 + 0] = w4.x; wv[i * 4 + 1] = w4.y;
    wv[i * 4 + 2] = w4.z; wv[i * 4 + 3] = w4.w;
  }
  unsigned* WAb = WA + (size_t)b * 65536;
  for (int dg = 0; dg < 16; ++dg) {
    float s[4];
#pragma unroll
    for (int j = 0; j < 4; ++j) {
      const int d = dg * 4 + j;
      float a0 = 0, a1 = 0;
#pragma unroll
      for (int e = 0; e < 64; e += 2) {
        a0 = fmaf(wv[e], Cb[d * 64 + e], a0);
        a1 = fmaf(wv[e + 1], Cb[d * 64 + e + 1], a1);
      }
      s[j] = a0 + a1;
    }
    const float4 ks = *(const float4*)&Kb[dg * 4];
    uint4 q4;
    q4.x = pack_bf(s[0] * (ATT_SCALE / (4096.0f * ks.x)));
    q4.y = pack_bf(s[1] * (ATT_SCALE / (4096.0f * ks.y)));
    q4.z = pack_bf(s[2] * (ATT_SCALE / (4096.0f * ks.z)));
    q4.w = pack_bf(s[3] * (ATT_SCALE / (4096.0f * ks.w)));
    const int wnd = h * 2 + (dg >> 3);
    const int slot = (dg & 7) ^ (o & 7);
    *(uint4*)&WAb[(size_t)wnd * 8192 + o * 32 + slot * 4] = q4;
  }
}

// ---------------------------------------------------------------------------
// K5 v3: y = WA GEMM over pre-exp'd packed q + deferred per-head 1/s + bias+LN.
// No softmax phase, no pack VALU — relayout is pure u32 moves. Per-head 1/s
// folded at head boundaries (kc&1): yacc += atmp * rs[h][col].
// ---------------------------------------------------------------------------
__global__ __launch_bounds__(512, 1) void k_final3(const unsigned* __restrict__ QKVP,
                                                   const unsigned* __restrict__ WA,
                                                   const float* __restrict__ QSUM,
                                                   const float* __restrict__ bout,
                                                   const float* __restrict__ gin,
                                                   float* __restrict__ OUT) {
  __shared__ __align__(16) unsigned Ubuf[16384];   // [256 m][64 col] -> QT [64][256]
  __shared__ __align__(16) unsigned AS[2][8192];   // [buf][256 o][32 m]
  __shared__ float csum[64], csq[64];
  __shared__ float bo_s[256], g_s[256];

  const int t = threadIdx.x;
  const int lane = t & 63;
  const int w = t >> 6;
  const int wm = w >> 1, wn = w & 1;
  const int r = lane & 15, gq = lane >> 4;
  const int b = blockIdx.y;
  const int n0 = blockIdx.x * 64;

  if (t < 64) { csum[t] = 0.f; csq[t] = 0.f; }
  if (t < 256) bo_s[t] = bout[t];
  else g_s[t - 256] = gin[t - 256];

  const unsigned* Qsrc = QKVP + (size_t)b * MQKV * NPIX + n0;
  const unsigned* WAb = WA + (size_t)b * 65536;

  // stage packed exp(q) tile [256 m][64 col] + AS chunk 0 (all threads)
#pragma unroll
  for (int i = 0; i < 8; ++i) {
    const int s = i * 512 + t;
    const int row = s >> 4, c16 = s & 15;
    gload_lds16(Qsrc + (size_t)row * NPIX + c16 * 4, (char*)Ubuf + (size_t)s * 16);
  }
#pragma unroll
  for (int q = 0; q < 4; ++q) {
    const int s = q * 512 + t;
    gload_lds16(WAb + s * 4, (char*)&AS[0][0] + s * 16);
  }
  __syncthreads();

  // relayout [m][col] -> QT[col][m] swizzled (pure u32 moves)
  {
    const int col = t & 63, w8 = t >> 6;
    unsigned pkv[32];
#pragma unroll
    for (int i = 0; i < 32; ++i)
      pkv[i] = Ubuf[(w8 * 32 + i) * 64 + col];
    __syncthreads();
#pragma unroll
    for (int p = 0; p < 8; ++p) {
      uint4 q4;
      q4.x = pkv[p * 4 + 0]; q4.y = pkv[p * 4 + 1];
      q4.z = pkv[p * 4 + 2]; q4.w = pkv[p * 4 + 3];
      *(uint4*)&Ubuf[col * 256 + w8 * 32 + ((p ^ (col & 7)) * 4)] = q4;
    }
  }
  __syncthreads();

  // GEMM: K=256 in 8 chunks; head = kc>>1; fold 1/s at head boundaries
  f32x4 yacc[4][2], atmp[4][2];
#pragma unroll
  for (int i = 0; i < 4; ++i)
#pragma unroll
    for (int j = 0; j < 2; ++j) {
      yacc[i][j] = (f32x4){0.f, 0.f, 0.f, 0.f};
      atmp[i][j] = (f32x4){0.f, 0.f, 0.f, 0.f};
    }

  for (int kc = 0; kc < 8; ++kc) {
    const int cur = kc & 1, nxt = cur ^ 1;
    if (kc < 7) {
#pragma unroll
      for (int q = 0; q < 4; ++q) {
        const int s = q * 512 + t;
        gload_lds16(WAb + (kc + 1) * 8192 + s * 4, (char*)&AS[nxt][0] + s * 16);
      }
    }
    s16x8 ah[4], al[4], bh[2], bl[2];
#pragma unroll
    for (int mt = 0; mt < 4; ++mt) {
      const int o = wm * 64 + mt * 16 + r;
      const uint4 u0 = *(const uint4*)&AS[cur][o * 32 + (((2 * gq) ^ (r & 7)) * 4)];
      const uint4 u1 = *(const uint4*)&AS[cur][o * 32 + (((2 * gq + 1) ^ (r & 7)) * 4)];
      s16x8 hv, lv;
      hv[0] = (short)(u0.x >> 16); lv[0] = (short)u0.x;
      hv[1] = (short)(u0.y >> 16); lv[1] = (short)u0.y;
      hv[2] = (short)(u0.z >> 16); lv[2] = (short)u0.z;
      hv[3] = (short)(u0.w >> 16); lv[3] = (short)u0.w;
      hv[4] = (short)(u1.x >> 16); lv[4] = (short)u1.x;
      hv[5] = (short)(u1.y >> 16); lv[5] = (short)u1.y;
      hv[6] = (short)(u1.z >> 16); lv[6] = (short)u1.z;
      hv[7] = (short)(u1.w >> 16); lv[7] = (short)u1.w;
      ah[mt] = hv; al[mt] = lv;
    }
#pragma unroll
    for (int nt = 0; nt < 2; ++nt) {
      const int col = wn * 32 + nt * 16 + r;
      const uint4 u0 = *(const uint4*)&Ubuf[col * 256 + kc * 32 + (((2 * gq) ^ (r & 7)) * 4)];
      const uint4 u1 = *(const uint4*)&Ubuf[col * 256 + kc * 32 + (((2 * gq + 1) ^ (r & 7)) * 4)];
      s16x8 hv, lv;
      hv[0] = (short)(u0.x >> 16); lv[0] = (short)u0.x;
      hv[1] = (short)(u0.y >> 16); lv[1] = (short)u0.y;
      hv[2] = (short)(u0.z >> 16); lv[2] = (short)u0.z;
      hv[3] = (short)(u0.w >> 16); lv[3] = (short)u0.w;
      hv[4] = (short)(u1.x >> 16); lv[4] = (short)u1.x;
      hv[5] = (short)(u1.y >> 16); lv[5] = (short)u1.y;
      hv[6] = (short)(u1.z >> 16); lv[6] = (short)u1.z;
      hv[7] = (short)(u1.w >> 16); lv[7] = (short)u1.w;
      bh[nt] = hv; bl[nt] = lv;
    }
#pragma unroll
    for (int mt = 0; mt < 4; ++mt)
#pragma unroll
      for (int nt = 0; nt < 2; ++nt) {
        atmp[mt][nt] = __builtin_amdgcn_mfma_f32_16x16x32_bf16(ah[mt], bh[nt], atmp[mt][nt], 0, 0, 0);
        atmp[mt][nt] = __builtin_amdgcn_mfma_f32_16x16x32_bf16(ah[mt], bl[nt], atmp[mt][nt], 0, 0, 0);
        atmp[mt][nt] = __builtin_amdgcn_mfma_f32_16x16x32_bf16(al[mt], bh[nt], atmp[mt][nt], 0, 0, 0);
      }
    if (kc & 1) {
      const int hh = kc >> 1;
      float rsv[2];
#pragma unroll
      for (int nt = 0; nt < 2; ++nt)
        rsv[nt] = 1.0f / QSUM[((size_t)b * 4 + hh) * NPIX + n0 + wn * 32 + nt * 16 + r];
#pragma unroll
      for (int mt = 0; mt < 4; ++mt)
#pragma unroll
        for (int nt = 0; nt < 2; ++nt) {
#pragma unroll
          for (int j = 0; j < 4; ++j)
            yacc[mt][nt][j] = fmaf(atmp[mt][nt][j], rsv[nt], yacc[mt][nt][j]);
          atmp[mt][nt] = (f32x4){0.f, 0.f, 0.f, 0.f};
        }
    }
    __syncthreads();
  }

  // epilogue: bias + column LayerNorm + write
  float psum[2] = {0.f, 0.f}, psq[2] = {0.f, 0.f};
#pragma unroll
  for (int mt = 0; mt < 4; ++mt)
#pragma unroll
    for (int nt = 0; nt < 2; ++nt)
#pragma unroll
      for (int j = 0; j < 4; ++j) {
        const int o = wm * 64 + mt * 16 + gq * 4 + j;
        const float y = yacc[mt][nt][j] + bo_s[o];
        yacc[mt][nt][j] = y;
        psum[nt] += y;
        psq[nt] += y * y;
      }
#pragma unroll
  for (int nt = 0; nt < 2; ++nt) {
    const int col = wn * 32 + nt * 16 + r;
    atomicAdd(&csum[col], psum[nt]);
    atomicAdd(&csq[col], psq[nt]);
  }
  __syncthreads();
  float mean[2], rstd[2];
#pragma unroll
  for (int nt = 0; nt < 2; ++nt) {
    const int col = wn * 32 + nt * 16 + r;
    const float m = csum[col] * (1.0f / 256.0f);
    const float v = csq[col] * (1.0f / 256.0f) - m * m;
    mean[nt] = m;
    rstd[nt] = rsqrtf(v + LN_EPS);
  }
#pragma unroll
  for (int mt = 0; mt < 4; ++mt)
#pragma unroll
    for (int j = 0; j < 4; ++j) {
      const int o = wm * 64 + mt * 16 + gq * 4 + j;
      const float gm = g_s[o];
#pragma unroll
      for (int nt = 0; nt < 2; ++nt) {
        const int col = wn * 32 + nt * 16 + r;
        OUT[((size_t)b * HID + o) * NPIX + n0 + col] =
            (yacc[mt][nt][j] - mean[nt]) * rstd[nt] * gm;
      }
    }
}

// ---------------------------------------------------------------------------
extern "C" void kernel_launch(void* const* d_in, const int* in_sizes, int n_in,
                              void* d_out, int out_size, void* d_ws, size_t ws_size,
                              hipStream_t stream) {
  const float* x     = (const float*)d_in[0];
  const float* w_qkv = (const float*)d_in[1];
  const float* w_out = (const float*)d_in[2];
  const float* b_out = (const float*)d_in[3];
  const float* g     = (const float*)d_in[4];
  float* out = (float*)d_out;
  float* ws = (float*)d_ws;

  unsigned* QKVP = (unsigned*)(ws + OFF_QKV);
  float* KSUM = ws + OFF_KSUM;
  float* CTX  = ws + OFF_CTX;
  float* QSUM = ws + OFF_QSUM;
  unsigned* WA = (unsigned*)(ws + OFF_WA);
  ushort* WH  = (ushort*)(ws + OFF_WH);
  ushort* WL  = (ushort*)(ws + OFF_WL);

  // zero KSUM + CTX + QSUM (contiguous)
  hipMemsetAsync(KSUM, 0, (4096 + 262144 + 262144) * sizeof(float), stream);
  k_wsplit<<<96, 256, 0, stream>>>(w_qkv, WH, WL);
  k_qkv_mfma<<<dim3(3072), 256, 0, stream>>>(WH, WL, x, QKVP, KSUM, QSUM);
  k_context3<<<dim3(64, 8), 256, 0, stream>>>(QKVP, CTX);
  k_wct2<<<dim3(4, 16), 256, 0, stream>>>(w_out, CTX, KSUM, WA);
  k_final3<<<dim3(64, 16), 512, 0, stream>>>(QKVP, WA, QSUM, b_out, g, out);
}